// Round 3
// baseline (93.164 us; speedup 1.0000x reference)
//
#include <hip/hip_runtime.h>

// YOLO loss, fp32. pred/target: (B=4096, 14, 14, 30). Output: scalar fp32.
// Round 3: LDS-staged tiles. Global loads are fully coalesced float4 copies
// (8 line-requests per wave-instr vs ~64 for strided per-cell loads).
// Grid-stride over tiles with register prefetch of tile k+1 under compute of
// tile k (loads drain at the next barrier, right before ds_write).

#define TPB 256
#define CPT 256                    // cells per tile
#define F4T (CPT * 30 / 4)         // float4 per tensor per tile = 1920
#define NBLOCKS 512

__device__ __forceinline__ float cell_loss(const float* __restrict__ p,
                                           const float* __restrict__ t)
{
    const bool coo = t[4] > 0.0f;
    if (!coo) {
        float d4 = p[4] - t[4];
        float d9 = p[9] - t[9];
        return 0.5f * (d4 * d4 + d9 * d9);
    }
    const float inv14 = 1.0f / 14.0f;
    float p0x1 = p[0]*inv14 - 0.5f*p[2], p0y1 = p[1]*inv14 - 0.5f*p[3];
    float p0x2 = p[0]*inv14 + 0.5f*p[2], p0y2 = p[1]*inv14 + 0.5f*p[3];
    float p1x1 = p[5]*inv14 - 0.5f*p[7], p1y1 = p[6]*inv14 - 0.5f*p[8];
    float p1x2 = p[5]*inv14 + 0.5f*p[7], p1y2 = p[6]*inv14 + 0.5f*p[8];
    float tx1  = t[0]*inv14 - 0.5f*t[2], ty1  = t[1]*inv14 - 0.5f*t[3];
    float tx2  = t[0]*inv14 + 0.5f*t[2], ty2  = t[1]*inv14 + 0.5f*t[3];

    float at = (tx2 - tx1) * (ty2 - ty1);

    float w0 = fmaxf(fminf(p0x2, tx2) - fmaxf(p0x1, tx1), 0.0f);
    float h0 = fmaxf(fminf(p0y2, ty2) - fmaxf(p0y1, ty1), 0.0f);
    float inter0 = w0 * h0;
    float a0 = (p0x2 - p0x1) * (p0y2 - p0y1);
    float iou0 = inter0 / (a0 + at - inter0);

    float w1 = fmaxf(fminf(p1x2, tx2) - fmaxf(p1x1, tx1), 0.0f);
    float h1 = fmaxf(fminf(p1y2, ty2) - fmaxf(p1y1, ty1), 0.0f);
    float inter1 = w1 * h1;
    float a1 = (p1x2 - p1x1) * (p1y2 - p1y1);
    float iou1 = inter1 / (a1 + at - inter1);

    // jnp.argmax returns FIRST max -> box1 responsible only if strictly greater
    bool  r1      = iou1 > iou0;
    float max_iou = fmaxf(iou0, iou1);

    float prx = r1 ? p[5] : p[0], pry = r1 ? p[6] : p[1];
    float prw = r1 ? p[7] : p[2], prh = r1 ? p[8] : p[3];
    float prc = r1 ? p[9] : p[4];
    float trx = r1 ? t[5] : t[0], try_ = r1 ? t[6] : t[1];
    float trw = r1 ? t[7] : t[2], trh = r1 ? t[8] : t[3];
    float cnr = r1 ? p[4] : p[9];

    float dc = prc - max_iou;
    float contain = dc * dc;
    float not_contain = cnr * cnr;

    float dx = prx - trx, dy = pry - try_;
    float dw = sqrtf(prw) - sqrtf(trw);
    float dh = sqrtf(prh) - sqrtf(trh);
    float loc = dx * dx + dy * dy + dw * dw + dh * dh;

    float cls = 0.0f;
#pragma unroll
    for (int k = 10; k < 30; ++k) {
        float d = p[k] - t[k];
        cls += d * d;
    }
    return 5.0f * loc + contain + 0.5f * not_contain + cls;
}

__global__ __launch_bounds__(TPB) void yolo_cells(
    const float* __restrict__ pred, const float* __restrict__ targ,
    float* __restrict__ partial, int ncells)
{
    __shared__ float smem[CPT * 60];               // 61440 B: pred tile | targ tile
    float4* smem4 = reinterpret_cast<float4*>(smem);
    const float4* P4 = reinterpret_cast<const float4*>(pred);
    const float4* T4 = reinterpret_cast<const float4*>(targ);

    const int ntiles = (ncells + CPT - 1) / CPT;
    const long maxf4 = (long)ncells * 30 / 4 - 1;  // clamp for partial last tile
    const int tid = threadIdx.x;
    float acc = 0.0f;

    float4 reg[15];
    int tile = blockIdx.x;

    if (tile < ntiles) {
#pragma unroll
        for (int i = 0; i < 15; ++i) {
            int j = i * TPB + tid;                 // 0..3839 combined index
            bool isP = j < F4T;
            long g = (long)tile * F4T + (isP ? j : j - F4T);
            if (g > maxf4) g = maxf4;
            reg[i] = isP ? P4[g] : T4[g];
        }
    }

    while (tile < ntiles) {
        __syncthreads();                           // LDS free; drains prefetch vmcnt
#pragma unroll
        for (int i = 0; i < 15; ++i) smem4[i * TPB + tid] = reg[i];
        __syncthreads();                           // tile ready

        int next = tile + gridDim.x;
        if (next < ntiles) {                       // issue next-tile loads now;
#pragma unroll                                     // they fly under the compute below
            for (int i = 0; i < 15; ++i) {
                int j = i * TPB + tid;
                bool isP = j < F4T;
                long g = (long)next * F4T + (isP ? j : j - F4T);
                if (g > maxf4) g = maxf4;
                reg[i] = isP ? P4[g] : T4[g];
            }
        }

        int cell = tile * CPT + tid;
        if (cell < ncells) {
            const float* p = smem + tid * 30;
            const float* t = smem + CPT * 30 + tid * 30;
            acc += cell_loss(p, t);
        }
        tile = next;
    }

    __shared__ float red[TPB];
    red[tid] = acc;
    __syncthreads();
#pragma unroll
    for (int s = TPB / 2; s > 0; s >>= 1) {
        if (tid < s) red[tid] += red[tid + s];
        __syncthreads();
    }
    if (tid == 0) partial[blockIdx.x] = red[0];
}

__global__ __launch_bounds__(256) void yolo_final(
    const float* __restrict__ partial, int n, float* __restrict__ out, float invN)
{
    __shared__ float sm[256];
    float acc = 0.0f;
    for (int i = threadIdx.x; i < n; i += 256) acc += partial[i];
    sm[threadIdx.x] = acc;
    __syncthreads();
#pragma unroll
    for (int s = 128; s > 0; s >>= 1) {
        if (threadIdx.x < s) sm[threadIdx.x] += sm[threadIdx.x + s];
        __syncthreads();
    }
    if (threadIdx.x == 0) out[0] = sm[0] * invN;
}

extern "C" void kernel_launch(void* const* d_in, const int* in_sizes, int n_in,
                              void* d_out, int out_size, void* d_ws, size_t ws_size,
                              hipStream_t stream) {
    const float* pred = (const float*)d_in[0];
    const float* targ = (const float*)d_in[1];
    float* out = (float*)d_out;
    float* partial = (float*)d_ws;

    const int ncells = in_sizes[0] / 30;           // B * 14 * 14
    const int B      = ncells / 196;
    const float invN = 1.0f / (float)B;

    const int ntiles = (ncells + CPT - 1) / CPT;   // 3136 for B=4096
    const int nblocks = ntiles < NBLOCKS ? ntiles : NBLOCKS;

    yolo_cells<<<nblocks, TPB, 0, stream>>>(pred, targ, partial, ncells);
    yolo_final<<<1, 256, 0, stream>>>(partial, nblocks, out, invN);
}

// Round 4
// 36.623 us; speedup vs baseline: 2.5439x; 2.5439x over previous
//
#include <hip/hip_runtime.h>

// YOLO loss, fp32. pred/target: (B=4096, 14, 14, 30). Output: scalar fp32.
// Round 4: wave-autonomous tiles staged via global_load_lds (direct HBM->LDS
// DMA, no VGPR staging -> no spill), per-wave double buffer with counted
// s_waitcnt vmcnt(15) (T4) and NO __syncthreads in the loop.
// 1 wave/block, 30.7 KB LDS -> 5 blocks/CU, ~77 KB/CU loads in flight.

#define CPW 64                    // cells per wave-tile
#define F4P 480                   // float4 per tensor per tile (64*30/4... 64*120B/16)
#define F4C (2 * F4P)             // combined float4 per tile = 960
#define LPI 15                    // load instrs per lane per tile (960/64)
#define MAXBLK 1280               // 5 blocks/CU * 256 CU

__device__ __forceinline__ void gload_lds16(const void* g, void* s) {
    // CK-style addrspace casts: as1 global src (per-lane), as3 LDS dest
    // (wave-uniform base; HW writes base + lane*16).
    auto g1 = (const __attribute__((address_space(1))) void*)(uintptr_t)g;
    auto s3 = (__attribute__((address_space(3))) void*)(uint32_t)(uintptr_t)s;
    __builtin_amdgcn_global_load_lds(g1, s3, 16, 0, 0);
}

__device__ __forceinline__ float cell_loss(const float* __restrict__ p,
                                           const float* __restrict__ t)
{
    const bool coo = t[4] > 0.0f;
    if (!coo) {
        float d4 = p[4] - t[4];
        float d9 = p[9] - t[9];
        return 0.5f * (d4 * d4 + d9 * d9);
    }
    const float inv14 = 1.0f / 14.0f;
    float p0x1 = p[0]*inv14 - 0.5f*p[2], p0y1 = p[1]*inv14 - 0.5f*p[3];
    float p0x2 = p[0]*inv14 + 0.5f*p[2], p0y2 = p[1]*inv14 + 0.5f*p[3];
    float p1x1 = p[5]*inv14 - 0.5f*p[7], p1y1 = p[6]*inv14 - 0.5f*p[8];
    float p1x2 = p[5]*inv14 + 0.5f*p[7], p1y2 = p[6]*inv14 + 0.5f*p[8];
    float tx1  = t[0]*inv14 - 0.5f*t[2], ty1  = t[1]*inv14 - 0.5f*t[3];
    float tx2  = t[0]*inv14 + 0.5f*t[2], ty2  = t[1]*inv14 + 0.5f*t[3];

    float at = (tx2 - tx1) * (ty2 - ty1);

    float w0 = fmaxf(fminf(p0x2, tx2) - fmaxf(p0x1, tx1), 0.0f);
    float h0 = fmaxf(fminf(p0y2, ty2) - fmaxf(p0y1, ty1), 0.0f);
    float inter0 = w0 * h0;
    float a0 = (p0x2 - p0x1) * (p0y2 - p0y1);
    float iou0 = inter0 / (a0 + at - inter0);

    float w1 = fmaxf(fminf(p1x2, tx2) - fmaxf(p1x1, tx1), 0.0f);
    float h1 = fmaxf(fminf(p1y2, ty2) - fmaxf(p1y1, ty1), 0.0f);
    float inter1 = w1 * h1;
    float a1 = (p1x2 - p1x1) * (p1y2 - p1y1);
    float iou1 = inter1 / (a1 + at - inter1);

    // jnp.argmax returns FIRST max -> box1 responsible only if strictly greater
    bool  r1      = iou1 > iou0;
    float max_iou = fmaxf(iou0, iou1);

    float prx = r1 ? p[5] : p[0], pry = r1 ? p[6] : p[1];
    float prw = r1 ? p[7] : p[2], prh = r1 ? p[8] : p[3];
    float prc = r1 ? p[9] : p[4];
    float trx = r1 ? t[5] : t[0], try_ = r1 ? t[6] : t[1];
    float trw = r1 ? t[7] : t[2], trh = r1 ? t[8] : t[3];
    float cnr = r1 ? p[4] : p[9];

    float dc = prc - max_iou;
    float contain = dc * dc;
    float not_contain = cnr * cnr;

    float dx = prx - trx, dy = pry - try_;
    float dw = sqrtf(prw) - sqrtf(trw);
    float dh = sqrtf(prh) - sqrtf(trh);
    float loc = dx * dx + dy * dy + dw * dw + dh * dh;

    float cls = 0.0f;
#pragma unroll
    for (int k = 10; k < 30; ++k) {
        float d = p[k] - t[k];
        cls += d * d;
    }
    return 5.0f * loc + contain + 0.5f * not_contain + cls;
}

__global__ __launch_bounds__(64) void yolo_cells(
    const float* __restrict__ pred, const float* __restrict__ targ,
    float* __restrict__ partial, int ncells)
{
    __shared__ float4 smem4[2][F4C];               // 2 x 15360 B
    const float4* P4 = reinterpret_cast<const float4*>(pred);
    const float4* T4 = reinterpret_cast<const float4*>(targ);

    const int  lane   = threadIdx.x;               // 64-thread block = 1 wave
    const int  wtiles = (ncells + CPW - 1) / CPW;
    const long maxf4  = (long)ncells * 30 / 4 - 1; // per-tensor clamp

    float acc = 0.0f;
    int tile = blockIdx.x;

    // prologue: stage first tile into buffer 0
    if (tile < wtiles) {
#pragma unroll
        for (int i = 0; i < LPI; ++i) {
            int  j   = i * 64 + lane;
            bool isP = j < F4P;
            long g   = (long)tile * F4P + (isP ? j : j - F4P);
            if (g > maxf4) g = maxf4;
            gload_lds16(isP ? (const void*)(P4 + g) : (const void*)(T4 + g),
                        (void*)&smem4[0][i * 64]);
        }
    }

    int buf = 0;
    for (; tile < wtiles; tile += gridDim.x) {
        int next = tile + gridDim.x;
        if (next < wtiles) {
            // issue next tile's loads into the other buffer, then wait only
            // for THIS tile's batch (counted vmcnt, never 0 mid-loop).
#pragma unroll
            for (int i = 0; i < LPI; ++i) {
                int  j   = i * 64 + lane;
                bool isP = j < F4P;
                long g   = (long)next * F4P + (isP ? j : j - F4P);
                if (g > maxf4) g = maxf4;
                gload_lds16(isP ? (const void*)(P4 + g) : (const void*)(T4 + g),
                            (void*)&smem4[buf ^ 1][i * 64]);
            }
            asm volatile("s_waitcnt vmcnt(15)" ::: "memory");
        } else {
            asm volatile("s_waitcnt vmcnt(0)" ::: "memory");
        }
        __builtin_amdgcn_sched_barrier(0);

        const float* base = reinterpret_cast<const float*>(&smem4[buf][0]);
        int cell = tile * CPW + lane;
        if (cell < ncells)
            acc += cell_loss(base + lane * 30, base + F4P * 4 + lane * 30);
        buf ^= 1;
    }

    // wave reduction, one partial per block
#pragma unroll
    for (int off = 32; off > 0; off >>= 1)
        acc += __shfl_down(acc, off, 64);
    if (lane == 0) partial[blockIdx.x] = acc;
}

__global__ __launch_bounds__(256) void yolo_final(
    const float* __restrict__ partial, int n, float* __restrict__ out, float invN)
{
    __shared__ float sm[256];
    float acc = 0.0f;
    for (int i = threadIdx.x; i < n; i += 256) acc += partial[i];
    sm[threadIdx.x] = acc;
    __syncthreads();
#pragma unroll
    for (int s = 128; s > 0; s >>= 1) {
        if (threadIdx.x < s) sm[threadIdx.x] += sm[threadIdx.x + s];
        __syncthreads();
    }
    if (threadIdx.x == 0) out[0] = sm[0] * invN;
}

extern "C" void kernel_launch(void* const* d_in, const int* in_sizes, int n_in,
                              void* d_out, int out_size, void* d_ws, size_t ws_size,
                              hipStream_t stream) {
    const float* pred = (const float*)d_in[0];
    const float* targ = (const float*)d_in[1];
    float* out = (float*)d_out;
    float* partial = (float*)d_ws;                 // MAXBLK floats = 5 KB

    const int ncells = in_sizes[0] / 30;           // B * 14 * 14
    const int B      = ncells / 196;
    const float invN = 1.0f / (float)B;

    const int wtiles  = (ncells + CPW - 1) / CPW;  // 12544 for B=4096
    const int nblocks = wtiles < MAXBLK ? wtiles : MAXBLK;

    yolo_cells<<<nblocks, 64, 0, stream>>>(pred, targ, partial, ncells);
    yolo_final<<<1, 256, 0, stream>>>(partial, nblocks, out, invN);
}